// Round 12
// baseline (68.662 us; speedup 1.0000x reference)
//
#include <hip/hip_runtime.h>
#include <hip/hip_bf16.h>

// Problem constants (N,C,H,W) = (32,256,56,56), GROUPS=8
#define NN 32
#define CC 256
#define HW 3136            // H*W
#define HW4 784            // float4 per (n,c) plane
#define CHW 802816
#define CHW4 200704        // float4 per sample
#define NCHW 25690112
#define GROUPS 8
#define CPG 32             // C/GROUPS
#define NHW 100352         // N*H*W (per-channel count)
#define GHW 100352         // CPG*HW (per-group count)
#define EPSF 1e-5f

#define PB16 49            // 16-f4 position blocks per sample (49*16 = 784)
#define NSTAT (NN*PB16)    // 1568 stats blocks
#define NPT2 NSTAT         // 1568 T^2 partials

typedef float f32x4 __attribute__((ext_vector_type(4)));

// ---- kernel 1: ONE read of x -> per-(n,c,pb) {S1,S2} float2 partials + T^2
__global__ __launch_bounds__(256) void stats_kernel(
    const float4* __restrict__ x4,
    float2* __restrict__ S12p,          // [NSTAT][256] {s1,s2}
    float* __restrict__ pT2)            // [NSTAT]
{
    const int bx = blockIdx.x;
    const int n = bx / PB16, pb = bx - n * PB16;
    const int tid = threadIdx.x;
    const int w = tid >> 6, lane = tid & 63;
    const int cl = lane >> 3;          // channel-local 0..7
    const int pl = lane & 7;           // position-local 0..7
    const int P0 = pb * 16;

    const float4* base = x4 + (size_t)n * CHW4 + P0 + pl;

    float s1a[8], s2a[8];
    float4 T0 = make_float4(0.f, 0.f, 0.f, 0.f);
    float4 T1 = make_float4(0.f, 0.f, 0.f, 0.f);
    #pragma unroll
    for (int k = 0; k < 8; ++k) {
        const int c = (k * 4 + w) * 8 + cl;
        float4 v0 = base[(size_t)c * HW4];
        float4 v1 = base[(size_t)c * HW4 + 8];
        T0.x += v0.x; T0.y += v0.y; T0.z += v0.z; T0.w += v0.w;
        T1.x += v1.x; T1.y += v1.y; T1.z += v1.z; T1.w += v1.w;
        s1a[k] = v0.x + v0.y + v0.z + v0.w + v1.x + v1.y + v1.z + v1.w;
        s2a[k] = v0.x*v0.x + v0.y*v0.y + v0.z*v0.z + v0.w*v0.w
               + v1.x*v1.x + v1.y*v1.y + v1.z*v1.z + v1.w*v1.w;
    }

    // per-channel partials: reduce over the 8 p-lanes (consecutive lanes)
    #pragma unroll
    for (int k = 0; k < 8; ++k) {
        #pragma unroll
        for (int off = 1; off < 8; off <<= 1) {
            s1a[k] += __shfl_down(s1a[k], off, 64);
            s2a[k] += __shfl_down(s2a[k], off, 64);
        }
    }
    if (pl == 0) {
        #pragma unroll
        for (int k = 0; k < 8; ++k) {
            const int c = (k * 4 + w) * 8 + cl;
            S12p[(size_t)bx * 256 + c] = make_float2(s1a[k], s2a[k]);
        }
    }

    // cross-channel T: reduce over the 8 c_local lanes (stride 8)
    #pragma unroll
    for (int off = 8; off < 64; off <<= 1) {
        T0.x += __shfl_xor(T0.x, off, 64);
        T0.y += __shfl_xor(T0.y, off, 64);
        T0.z += __shfl_xor(T0.z, off, 64);
        T0.w += __shfl_xor(T0.w, off, 64);
        T1.x += __shfl_xor(T1.x, off, 64);
        T1.y += __shfl_xor(T1.y, off, 64);
        T1.z += __shfl_xor(T1.z, off, 64);
        T1.w += __shfl_xor(T1.w, off, 64);
    }
    __shared__ float4 shT[4][16];
    if (lane < 8) {                    // cl==0 lanes hold the reduced sums
        shT[w][pl] = T0;
        shT[w][8 + pl] = T1;
    }
    __syncthreads();
    if (tid < 16) {
        float4 a = shT[0][tid], b = shT[1][tid], c4 = shT[2][tid], d = shT[3][tid];
        const float tx = a.x + b.x + c4.x + d.x;
        const float ty = a.y + b.y + c4.y + d.y;
        const float tz = a.z + b.z + c4.z + d.z;
        const float tw = a.w + b.w + c4.w + d.w;
        float t2 = tx*tx + ty*ty + tz*tz + tw*tw;
        #pragma unroll
        for (int off = 1; off < 16; off <<= 1) t2 += __shfl_down(t2, off, 64);
        if (tid == 0) pT2[bx] = t2;
    }
}

// ---- kernel 2: fold (32 blocks) + finalize (last block via ticket) -------
//  CB[c]  = {mu_b, rs_b};  CL[n] = {mu_l, rs_l};  CG[ng] = {mu_g, rs_g};
//  GT[0..2] = softmax gates.  ticket must be 0 at launch.
__global__ __launch_bounds__(256) void fold_finalize_kernel(
    const float2* __restrict__ S12p, const float* __restrict__ partialT2,
    const float* __restrict__ gate_logits, const float* __restrict__ diag_proj,
    float2* __restrict__ S12,
    float2* __restrict__ CB, float2* __restrict__ CL, float2* __restrict__ CG,
    float* __restrict__ GT, unsigned* ticket)
{
    const int tid = threadIdx.x;

    // ---- fold phase: block n folds sample n ----
    {
        const int n = blockIdx.x;
        const float2* p = S12p + (size_t)n * PB16 * 256 + tid;
        float a = 0.f, b = 0.f;
        #pragma unroll 7
        for (int pb = 0; pb < PB16; ++pb) {
            float2 v = p[(size_t)pb * 256];
            a += v.x; b += v.y;
        }
        S12[n * 256 + tid] = make_float2(a, b);
    }

    // ---- last-block-done ticket ----
    __shared__ bool sh_last;
    __syncthreads();
    if (tid == 0) {
        __threadfence();                               // release S12 writes
        unsigned old = atomicAdd(ticket, 1u);
        sh_last = (old == NN - 1u);
    }
    __syncthreads();
    if (!sh_last) return;
    __threadfence();                                   // acquire others' S12

    // ---- finalize phase (single surviving block) ----
    __shared__ float sh_red1[4], sh_red2[4], sh_red3[4], sh_red4[4];

    const float inv_NHW  = 1.f / (float)NHW;
    const float inv_CHW  = 1.f / (float)CHW;
    const float inv_GHW  = 1.f / (float)GHW;
    const float inv_NCHW = 1.f / (float)NCHW;

    // BN: thread = channel
    const int c = tid;
    float s1 = 0.f, s2 = 0.f;
    for (int n = 0; n < NN; ++n) {
        float2 v = S12[n * CC + c];
        s1 += v.x; s2 += v.y;
    }
    const float mu_b  = s1 * inv_NHW;
    const float var_b = s2 * inv_NHW - mu_b * mu_b;
    CB[c] = make_float2(mu_b, rsqrtf(var_b + EPSF));

    // GN: thread = n*8+g
    const int ng_n = tid >> 3, ng_g = tid & 7;
    float s1g = 0.f, s2g = 0.f;
    for (int cc2 = 0; cc2 < CPG; ++cc2) {
        float2 v = S12[ng_n * CC + ng_g * CPG + cc2];
        s1g += v.x; s2g += v.y;
    }
    const float mu_g  = s1g * inv_GHW;
    const float var_g = s2g * inv_GHW - mu_g * mu_g;
    CG[tid] = make_float2(mu_g, rsqrtf(var_g + EPSF));

    // LN: reduce GN sums over the 8 groups of each sample
    float s1l = s1g, s2l = s2g;
    #pragma unroll
    for (int off = 1; off < 8; off <<= 1) {
        s1l += __shfl_xor(s1l, off, 64);
        s2l += __shfl_xor(s2l, off, 64);
    }
    float var_l_contrib = 0.f;
    if (ng_g == 0) {
        const float mu_l  = s1l * inv_CHW;
        const float var_l = s2l * inv_CHW - mu_l * mu_l;
        CL[ng_n] = make_float2(mu_l, rsqrtf(var_l + EPSF));
        var_l_contrib = var_l;
    }

    // T^2 partials
    float t2p = 0.f;
    for (int i = tid; i < NPT2; i += 256) t2p += partialT2[i];

    float r1 = var_b, r2 = s2, r3 = var_l_contrib, r4 = t2p;
    #pragma unroll
    for (int off = 32; off; off >>= 1) {
        r1 += __shfl_down(r1, off, 64);
        r2 += __shfl_down(r2, off, 64);
        r3 += __shfl_down(r3, off, 64);
        r4 += __shfl_down(r4, off, 64);
    }
    const int wave = tid >> 6, lane = tid & 63;
    if (lane == 0) { sh_red1[wave] = r1; sh_red2[wave] = r2; sh_red3[wave] = r3; sh_red4[wave] = r4; }
    __syncthreads();
    if (tid == 0) {
        const float sum_var_b = sh_red1[0] + sh_red1[1] + sh_red1[2] + sh_red1[3];
        const float total_x2  = sh_red2[0] + sh_red2[1] + sh_red2[2] + sh_red2[3];
        const float sum_var_l = sh_red3[0] + sh_red3[1] + sh_red3[2] + sh_red3[3];
        const float sum_T2    = sh_red4[0] + sh_red4[1] + sh_red4[2] + sh_red4[3];

        const float batch_var   = sum_var_b * (1.f / (float)CC);
        const float sample_var  = sum_var_l * (1.f / (float)NN);
        const float channel_var = total_x2 * inv_NCHW
                                - sum_T2 * inv_NHW * (1.f / ((float)CC * (float)CC));

        float desc[3];
        desc[0] = tanhf(logf(fmaxf(batch_var,   EPSF)));
        desc[1] = tanhf(logf(fmaxf(sample_var,  EPSF)));
        desc[2] = tanhf(logf(fmaxf(channel_var, EPSF)));

        float lg[3];
        #pragma unroll
        for (int i = 0; i < 3; ++i) {
            lg[i] = gate_logits[i] + diag_proj[i*3+0]*desc[0]
                                   + diag_proj[i*3+1]*desc[1]
                                   + diag_proj[i*3+2]*desc[2];
        }
        const float m = fmaxf(lg[0], fmaxf(lg[1], lg[2]));
        const float e0 = expf(lg[0]-m), e1 = expf(lg[1]-m), e2 = expf(lg[2]-m);
        const float inv = 1.f / (e0 + e1 + e2);
        GT[0] = e0 * inv; GT[1] = e1 * inv; GT[2] = e2 * inv;
    }
}

// ---- kernel 3: y = x*a + b; 2 planes per block; nt stores ----------------
__global__ __launch_bounds__(256) void apply_kernel(
    const f32x4* __restrict__ x4,
    const float* __restrict__ weight, const float* __restrict__ bias,
    const float2* __restrict__ CB, const float2* __restrict__ CL,
    const float2* __restrict__ CG, const float* __restrict__ GT,
    f32x4* __restrict__ y4)
{
    const int nc0 = blockIdx.x * 2, nc1 = nc0 + 1;
    const float g0 = GT[0], g1 = GT[1], g2 = GT[2];

    const int n0 = nc0 >> 8, ch0 = nc0 & 255, gg0 = ch0 >> 5;
    const float2 cb0 = CB[ch0], cl0 = CL[n0], cg0 = CG[n0 * 8 + gg0];
    const float w0 = weight[ch0], bi0 = bias[ch0];
    const float a0 = w0 * (g0 * cb0.y + g1 * cl0.y + g2 * cg0.y);
    const float b0 = fmaf(-w0, g0 * cb0.x * cb0.y + g1 * cl0.x * cl0.y + g2 * cg0.x * cg0.y, bi0);

    const int n1 = nc1 >> 8, ch1 = nc1 & 255, gg1 = ch1 >> 5;
    const float2 cb1 = CB[ch1], cl1 = CL[n1], cg1 = CG[n1 * 8 + gg1];
    const float w1 = weight[ch1], bi1 = bias[ch1];
    const float a1 = w1 * (g0 * cb1.y + g1 * cl1.y + g2 * cg1.y);
    const float b1 = fmaf(-w1, g0 * cb1.x * cb1.y + g1 * cl1.x * cl1.y + g2 * cg1.x * cg1.y, bi1);

    const f32x4* xp0 = x4 + (size_t)nc0 * HW4;
    const f32x4* xp1 = x4 + (size_t)nc1 * HW4;
    f32x4* yp0 = y4 + (size_t)nc0 * HW4;
    f32x4* yp1 = y4 + (size_t)nc1 * HW4;
    const int tid = threadIdx.x;

    // batch all independent loads (up to 8 in flight), then fma + nt store
    f32x4 u0 = xp0[tid];
    f32x4 u1 = xp0[tid + 256];
    f32x4 u2 = xp0[tid + 512];
    f32x4 v0 = xp1[tid];
    f32x4 v1 = xp1[tid + 256];
    f32x4 v2 = xp1[tid + 512];
    f32x4 u3, v3;
    if (tid < 16) { u3 = xp0[tid + 768]; v3 = xp1[tid + 768]; }

    f32x4 r;
    r.x = fmaf(u0.x, a0, b0); r.y = fmaf(u0.y, a0, b0); r.z = fmaf(u0.z, a0, b0); r.w = fmaf(u0.w, a0, b0);
    __builtin_nontemporal_store(r, &yp0[tid]);
    r.x = fmaf(u1.x, a0, b0); r.y = fmaf(u1.y, a0, b0); r.z = fmaf(u1.z, a0, b0); r.w = fmaf(u1.w, a0, b0);
    __builtin_nontemporal_store(r, &yp0[tid + 256]);
    r.x = fmaf(u2.x, a0, b0); r.y = fmaf(u2.y, a0, b0); r.z = fmaf(u2.z, a0, b0); r.w = fmaf(u2.w, a0, b0);
    __builtin_nontemporal_store(r, &yp0[tid + 512]);
    r.x = fmaf(v0.x, a1, b1); r.y = fmaf(v0.y, a1, b1); r.z = fmaf(v0.z, a1, b1); r.w = fmaf(v0.w, a1, b1);
    __builtin_nontemporal_store(r, &yp1[tid]);
    r.x = fmaf(v1.x, a1, b1); r.y = fmaf(v1.y, a1, b1); r.z = fmaf(v1.z, a1, b1); r.w = fmaf(v1.w, a1, b1);
    __builtin_nontemporal_store(r, &yp1[tid + 256]);
    r.x = fmaf(v2.x, a1, b1); r.y = fmaf(v2.y, a1, b1); r.z = fmaf(v2.z, a1, b1); r.w = fmaf(v2.w, a1, b1);
    __builtin_nontemporal_store(r, &yp1[tid + 512]);
    if (tid < 16) {
        r.x = fmaf(u3.x, a0, b0); r.y = fmaf(u3.y, a0, b0); r.z = fmaf(u3.z, a0, b0); r.w = fmaf(u3.w, a0, b0);
        __builtin_nontemporal_store(r, &yp0[tid + 768]);
        r.x = fmaf(v3.x, a1, b1); r.y = fmaf(v3.y, a1, b1); r.z = fmaf(v3.z, a1, b1); r.w = fmaf(v3.w, a1, b1);
        __builtin_nontemporal_store(r, &yp1[tid + 768]);
    }
}

extern "C" void kernel_launch(void* const* d_in, const int* in_sizes, int n_in,
                              void* d_out, int out_size, void* d_ws, size_t ws_size,
                              hipStream_t stream) {
    const float* x           = (const float*)d_in[0];
    const float* weight      = (const float*)d_in[1];
    const float* bias        = (const float*)d_in[2];
    const float* gate_logits = (const float*)d_in[3];
    const float* diag_proj   = (const float*)d_in[4];
    float* out = (float*)d_out;

    // ws layout (float offsets; float2 users even-aligned, f4 users 4-aligned)
    float* ws   = (float*)d_ws;
    float2* S12p = (float2*)ws;                  // NSTAT*256 float2 = 802816 f
    float2* S12  = (float2*)(ws + 802816);       // 8192 float2 = 16384 f
    float2* CB   = (float2*)(ws + 819200);       // 256 float2
    float2* CL   = (float2*)(ws + 819712);       // 32 float2
    float2* CG   = (float2*)(ws + 819776);       // 256 float2
    float*  GT   = ws + 820288;                  // 4
    float*  pT2  = ws + 820296;                  // 1568
    unsigned* ticket = (unsigned*)(ws + 821888); // 1 uint (16B-aligned)

    // ticket must be 0 at kernel start; captured as a graph node.
    hipMemsetAsync(ticket, 0, sizeof(unsigned), stream);

    stats_kernel<<<NSTAT, 256, 0, stream>>>((const float4*)x, S12p, pT2);
    fold_finalize_kernel<<<NN, 256, 0, stream>>>(S12p, pT2, gate_logits, diag_proj,
                                                 S12, CB, CL, CG, GT, ticket);
    apply_kernel<<<NN * CC / 2, 256, 0, stream>>>((const f32x4*)x, weight, bias,
                                                  CB, CL, CG, GT, (f32x4*)out);
}

// Round 13
// 62.967 us; speedup vs baseline: 1.0904x; 1.0904x over previous
//
#include <hip/hip_runtime.h>
#include <hip/hip_bf16.h>

// Problem constants (N,C,H,W) = (32,256,56,56), GROUPS=8
#define NN 32
#define CC 256
#define HW 3136            // H*W
#define HW4 784            // float4 per (n,c) plane
#define CHW 802816
#define CHW4 200704        // float4 per sample
#define NCHW 25690112
#define GROUPS 8
#define CPG 32             // C/GROUPS
#define NHW 100352         // N*H*W (per-channel count)
#define GHW 100352         // CPG*HW (per-group count)
#define EPSF 1e-5f

#define PB16 49            // 16-f4 position blocks per sample (49*16 = 784)
#define NSTAT (NN*PB16)    // 1568 stats blocks
#define NPT2 NSTAT         // 1568 T^2 partials

typedef float f32x4 __attribute__((ext_vector_type(4)));

// ---- kernel 1: ONE read of x -> per-(n,c,pb) {S1,S2} float2 partials + T^2
// block = (n, pb of 16 f4-positions); lane = (c_local 0..7, p 0..7);
// iter k: wave covers channels (k*4+w)*8 + c_local at the block's 16 positions.
// Epilogue per-channel reduce done via LDS transpose (not shuffles).
__global__ __launch_bounds__(256) void stats_kernel(
    const float4* __restrict__ x4,
    float2* __restrict__ S12p,          // [NSTAT][256] {s1,s2}
    float* __restrict__ pT2)            // [NSTAT]
{
    const int bx = blockIdx.x;
    const int n = bx / PB16, pb = bx - n * PB16;
    const int tid = threadIdx.x;
    const int w = tid >> 6, lane = tid & 63;
    const int cl = lane >> 3;          // channel-local 0..7
    const int pl = lane & 7;           // position-local 0..7
    const int P0 = pb * 16;

    const float4* base = x4 + (size_t)n * CHW4 + P0 + pl;

    __shared__ float2 shS[256][9];     // [channel][p-octet], +1 pad (<=2-way)
    __shared__ float4 shT[4][16];

    float s1a[8], s2a[8];
    float4 T0 = make_float4(0.f, 0.f, 0.f, 0.f);
    float4 T1 = make_float4(0.f, 0.f, 0.f, 0.f);
    #pragma unroll
    for (int k = 0; k < 8; ++k) {
        const int c = (k * 4 + w) * 8 + cl;
        float4 v0 = base[(size_t)c * HW4];
        float4 v1 = base[(size_t)c * HW4 + 8];
        T0.x += v0.x; T0.y += v0.y; T0.z += v0.z; T0.w += v0.w;
        T1.x += v1.x; T1.y += v1.y; T1.z += v1.z; T1.w += v1.w;
        s1a[k] = v0.x + v0.y + v0.z + v0.w + v1.x + v1.y + v1.z + v1.w;
        s2a[k] = v0.x*v0.x + v0.y*v0.y + v0.z*v0.z + v0.w*v0.w
               + v1.x*v1.x + v1.y*v1.y + v1.z*v1.z + v1.w*v1.w;
    }

    // scatter per-channel partials to LDS (conflict-free b64 writes)
    #pragma unroll
    for (int k = 0; k < 8; ++k) {
        const int c = (k * 4 + w) * 8 + cl;
        shS[c][pl] = make_float2(s1a[k], s2a[k]);
    }
    __syncthreads();

    // gather: thread tid = channel, linear sum of its 8 p-octet partials
    {
        float a = 0.f, b = 0.f;
        #pragma unroll
        for (int j = 0; j < 8; ++j) {
            float2 v = shS[tid][j];
            a += v.x; b += v.y;
        }
        S12p[(size_t)bx * 256 + tid] = make_float2(a, b);
    }

    // cross-channel T: reduce over the 8 c_local lanes (stride 8)
    #pragma unroll
    for (int off = 8; off < 64; off <<= 1) {
        T0.x += __shfl_xor(T0.x, off, 64);
        T0.y += __shfl_xor(T0.y, off, 64);
        T0.z += __shfl_xor(T0.z, off, 64);
        T0.w += __shfl_xor(T0.w, off, 64);
        T1.x += __shfl_xor(T1.x, off, 64);
        T1.y += __shfl_xor(T1.y, off, 64);
        T1.z += __shfl_xor(T1.z, off, 64);
        T1.w += __shfl_xor(T1.w, off, 64);
    }
    if (lane < 8) {                    // cl==0 lanes hold the reduced sums
        shT[w][pl] = T0;
        shT[w][8 + pl] = T1;
    }
    __syncthreads();
    if (tid < 16) {
        float4 a = shT[0][tid], b = shT[1][tid], c4 = shT[2][tid], d = shT[3][tid];
        const float tx = a.x + b.x + c4.x + d.x;
        const float ty = a.y + b.y + c4.y + d.y;
        const float tz = a.z + b.z + c4.z + d.z;
        const float tw = a.w + b.w + c4.w + d.w;
        float t2 = tx*tx + ty*ty + tz*tz + tw*tw;
        #pragma unroll
        for (int off = 1; off < 16; off <<= 1) t2 += __shfl_down(t2, off, 64);
        if (tid == 0) pT2[bx] = t2;
    }
}

// ---- kernel 2: fold 49 position-partials -> S12[n*256+c] -----------------
__global__ __launch_bounds__(256) void fold_kernel(
    const float2* __restrict__ S12p, float2* __restrict__ S12)
{
    const int n = blockIdx.x, c = threadIdx.x;
    const float2* p = S12p + (size_t)n * PB16 * 256 + c;
    float a = 0.f, b = 0.f;
    #pragma unroll 7
    for (int pb = 0; pb < PB16; ++pb) {
        float2 v = p[(size_t)pb * 256];
        a += v.x; b += v.y;
    }
    S12[n * 256 + c] = make_float2(a, b);
}

// ---- kernel 3: stats -> gates + compact norm coefficients ----------------
//  CB[c]  = {mu_b, rs_b};  CL[n] = {mu_l, rs_l};  CG[ng] = {mu_g, rs_g};
//  GT[0..2] = softmax gates
__global__ __launch_bounds__(256) void finalize_kernel(
    const float2* __restrict__ S12, const float* __restrict__ partialT2,
    const float* __restrict__ gate_logits, const float* __restrict__ diag_proj,
    float2* __restrict__ CB, float2* __restrict__ CL, float2* __restrict__ CG,
    float* __restrict__ GT)
{
    const int tid = threadIdx.x;
    __shared__ float sh_red1[4], sh_red2[4], sh_red3[4], sh_red4[4];

    const float inv_NHW  = 1.f / (float)NHW;
    const float inv_CHW  = 1.f / (float)CHW;
    const float inv_GHW  = 1.f / (float)GHW;
    const float inv_NCHW = 1.f / (float)NCHW;

    // BN: thread = channel
    const int c = tid;
    float s1 = 0.f, s2 = 0.f;
    for (int n = 0; n < NN; ++n) {
        float2 v = S12[n * CC + c];
        s1 += v.x; s2 += v.y;
    }
    const float mu_b  = s1 * inv_NHW;
    const float var_b = s2 * inv_NHW - mu_b * mu_b;
    CB[c] = make_float2(mu_b, rsqrtf(var_b + EPSF));

    // GN: thread = n*8+g
    const int ng_n = tid >> 3, ng_g = tid & 7;
    float s1g = 0.f, s2g = 0.f;
    for (int cc2 = 0; cc2 < CPG; ++cc2) {
        float2 v = S12[ng_n * CC + ng_g * CPG + cc2];
        s1g += v.x; s2g += v.y;
    }
    const float mu_g  = s1g * inv_GHW;
    const float var_g = s2g * inv_GHW - mu_g * mu_g;
    CG[tid] = make_float2(mu_g, rsqrtf(var_g + EPSF));

    // LN: reduce GN sums over the 8 groups of each sample
    float s1l = s1g, s2l = s2g;
    #pragma unroll
    for (int off = 1; off < 8; off <<= 1) {
        s1l += __shfl_xor(s1l, off, 64);
        s2l += __shfl_xor(s2l, off, 64);
    }
    float var_l_contrib = 0.f;
    if (ng_g == 0) {
        const float mu_l  = s1l * inv_CHW;
        const float var_l = s2l * inv_CHW - mu_l * mu_l;
        CL[ng_n] = make_float2(mu_l, rsqrtf(var_l + EPSF));
        var_l_contrib = var_l;
    }

    // T^2 partials
    float t2p = 0.f;
    for (int i = tid; i < NPT2; i += 256) t2p += partialT2[i];

    float r1 = var_b, r2 = s2, r3 = var_l_contrib, r4 = t2p;
    #pragma unroll
    for (int off = 32; off; off >>= 1) {
        r1 += __shfl_down(r1, off, 64);
        r2 += __shfl_down(r2, off, 64);
        r3 += __shfl_down(r3, off, 64);
        r4 += __shfl_down(r4, off, 64);
    }
    const int wave = tid >> 6, lane = tid & 63;
    if (lane == 0) { sh_red1[wave] = r1; sh_red2[wave] = r2; sh_red3[wave] = r3; sh_red4[wave] = r4; }
    __syncthreads();
    if (tid == 0) {
        const float sum_var_b = sh_red1[0] + sh_red1[1] + sh_red1[2] + sh_red1[3];
        const float total_x2  = sh_red2[0] + sh_red2[1] + sh_red2[2] + sh_red2[3];
        const float sum_var_l = sh_red3[0] + sh_red3[1] + sh_red3[2] + sh_red3[3];
        const float sum_T2    = sh_red4[0] + sh_red4[1] + sh_red4[2] + sh_red4[3];

        const float batch_var   = sum_var_b * (1.f / (float)CC);
        const float sample_var  = sum_var_l * (1.f / (float)NN);
        const float channel_var = total_x2 * inv_NCHW
                                - sum_T2 * inv_NHW * (1.f / ((float)CC * (float)CC));

        float desc[3];
        desc[0] = tanhf(logf(fmaxf(batch_var,   EPSF)));
        desc[1] = tanhf(logf(fmaxf(sample_var,  EPSF)));
        desc[2] = tanhf(logf(fmaxf(channel_var, EPSF)));

        float lg[3];
        #pragma unroll
        for (int i = 0; i < 3; ++i) {
            lg[i] = gate_logits[i] + diag_proj[i*3+0]*desc[0]
                                   + diag_proj[i*3+1]*desc[1]
                                   + diag_proj[i*3+2]*desc[2];
        }
        const float m = fmaxf(lg[0], fmaxf(lg[1], lg[2]));
        const float e0 = expf(lg[0]-m), e1 = expf(lg[1]-m), e2 = expf(lg[2]-m);
        const float inv = 1.f / (e0 + e1 + e2);
        GT[0] = e0 * inv; GT[1] = e1 * inv; GT[2] = e2 * inv;
    }
}

// ---- kernel 4: y = x*a + b; a,b computed per block; nt stores ------------
__global__ __launch_bounds__(256) void apply_kernel(
    const f32x4* __restrict__ x4,
    const float* __restrict__ weight, const float* __restrict__ bias,
    const float2* __restrict__ CB, const float2* __restrict__ CL,
    const float2* __restrict__ CG, const float* __restrict__ GT,
    f32x4* __restrict__ y4)
{
    const int nc = blockIdx.x;
    const int n = nc >> 8, ch = nc & 255, g = ch >> 5;
    const float g0 = GT[0], g1 = GT[1], g2 = GT[2];
    const float2 cb = CB[ch], cl2 = CL[n], cg2 = CG[n * 8 + g];
    const float w = weight[ch], bi = bias[ch];
    const float scale = g0 * cb.y + g1 * cl2.y + g2 * cg2.y;
    const float offs  = g0 * cb.x * cb.y + g1 * cl2.x * cl2.y + g2 * cg2.x * cg2.y;
    const float a = w * scale;
    const float b = fmaf(-w, offs, bi);

    const f32x4* xp = x4 + (size_t)nc * HW4;
    f32x4* yp = y4 + (size_t)nc * HW4;
    const int tid = threadIdx.x;

    // batch the independent loads (3 full strides + 16-wide tail), then store
    f32x4 v0 = xp[tid];
    f32x4 v1 = xp[tid + 256];
    f32x4 v2 = xp[tid + 512];
    f32x4 v3;
    if (tid < 16) v3 = xp[tid + 768];

    f32x4 r0, r1, r2, r3;
    r0.x = fmaf(v0.x, a, b); r0.y = fmaf(v0.y, a, b); r0.z = fmaf(v0.z, a, b); r0.w = fmaf(v0.w, a, b);
    r1.x = fmaf(v1.x, a, b); r1.y = fmaf(v1.y, a, b); r1.z = fmaf(v1.z, a, b); r1.w = fmaf(v1.w, a, b);
    r2.x = fmaf(v2.x, a, b); r2.y = fmaf(v2.y, a, b); r2.z = fmaf(v2.z, a, b); r2.w = fmaf(v2.w, a, b);
    __builtin_nontemporal_store(r0, &yp[tid]);
    __builtin_nontemporal_store(r1, &yp[tid + 256]);
    __builtin_nontemporal_store(r2, &yp[tid + 512]);
    if (tid < 16) {
        r3.x = fmaf(v3.x, a, b); r3.y = fmaf(v3.y, a, b); r3.z = fmaf(v3.z, a, b); r3.w = fmaf(v3.w, a, b);
        __builtin_nontemporal_store(r3, &yp[tid + 768]);
    }
}

extern "C" void kernel_launch(void* const* d_in, const int* in_sizes, int n_in,
                              void* d_out, int out_size, void* d_ws, size_t ws_size,
                              hipStream_t stream) {
    const float* x           = (const float*)d_in[0];
    const float* weight      = (const float*)d_in[1];
    const float* bias        = (const float*)d_in[2];
    const float* gate_logits = (const float*)d_in[3];
    const float* diag_proj   = (const float*)d_in[4];
    float* out = (float*)d_out;

    // ws layout (float offsets; all float2 users even-aligned)
    float* ws   = (float*)d_ws;
    float2* S12p = (float2*)ws;                  // NSTAT*256 float2 = 802816 f
    float2* S12  = (float2*)(ws + 802816);       // 8192 float2 = 16384 f
    float2* CB   = (float2*)(ws + 819200);       // 256 float2
    float2* CL   = (float2*)(ws + 819712);       // 32 float2
    float2* CG   = (float2*)(ws + 819776);       // 256 float2
    float*  GT   = ws + 820288;                  // 4
    float*  pT2  = ws + 820296;                  // 1568

    stats_kernel<<<NSTAT, 256, 0, stream>>>((const float4*)x, S12p, pT2);
    fold_kernel<<<NN, 256, 0, stream>>>(S12p, S12);
    finalize_kernel<<<1, 256, 0, stream>>>(S12, pT2, gate_logits, diag_proj,
                                           CB, CL, CG, GT);
    apply_kernel<<<NN * CC, 256, 0, stream>>>((const f32x4*)x, weight, bias,
                                              CB, CL, CG, GT, (f32x4*)out);
}

// Round 14
// 62.794 us; speedup vs baseline: 1.0935x; 1.0028x over previous
//
#include <hip/hip_runtime.h>
#include <hip/hip_bf16.h>

// Problem constants (N,C,H,W) = (32,256,56,56), GROUPS=8
#define NN 32
#define CC 256
#define HW4 784            // float4 per (n,c) plane
#define CHW4 200704        // float4 per sample
#define NCHW 25690112
#define GROUPS 8
#define CPG 32             // C/GROUPS
#define NHW 100352         // N*H*W (per-channel count)
#define GHW 100352         // CPG*HW (per-group count)
#define EPSF 1e-5f

#define WIN 13             // 64-f4 windows per plane (12 full + one 16-wide tail)
#define NSTAT (NN*WIN*4)   // 1664 stats blocks (x4 channel-quarters)
#define NPT2 NSTAT         // T^2 partials

typedef float f32x4 __attribute__((ext_vector_type(4)));

// ---- kernel 1: ONE read of x, fully-coalesced 1KB wave loads -------------
// block = (n, win of 64 f4-positions, q = channel-quarter of 64 channels);
// wave w owns 16 channels [q*64+w*16 .. +16); lane = f4-position in window.
// Per-channel sums via padded LDS transpose; cross-channel T is lane-local.
__global__ __launch_bounds__(256) void stats_kernel(
    const float4* __restrict__ x4,
    float2* __restrict__ S12p,          // [NN*WIN][256] {s1,s2}
    float* __restrict__ pT2)            // [NSTAT]
{
    const int bx = blockIdx.x;
    const int q   = bx & 3;
    const int nw  = bx >> 2;
    const int win = nw % WIN;
    const int n   = nw / WIN;
    const int tid = threadIdx.x;
    const int w   = tid >> 6, lane = tid & 63;

    const int p4 = win * 64 + lane;     // f4 position in plane
    const bool pv = p4 < HW4;           // tail window: only lanes 0..15 valid
    const int c0 = q * 64 + w * 16;     // first channel of this wave

    const float4* base = x4 + (size_t)n * CHW4 + p4;

    __shared__ float sh1[64][65];       // [c_local][lane], pitch 65 -> <=2-way
    __shared__ float sh2[64][65];
    __shared__ float4 shT[4][64];

    float4 T = make_float4(0.f, 0.f, 0.f, 0.f);
    #pragma unroll
    for (int k = 0; k < 16; ++k) {
        const int c = c0 + k;
        float4 v = make_float4(0.f, 0.f, 0.f, 0.f);
        if (pv) v = base[(size_t)c * HW4];          // 1KB contiguous per wave
        T.x += v.x; T.y += v.y; T.z += v.z; T.w += v.w;
        sh1[w * 16 + k][lane] = v.x + v.y + v.z + v.w;
        sh2[w * 16 + k][lane] = v.x*v.x + v.y*v.y + v.z*v.z + v.w*v.w;
    }
    shT[w][lane] = T;
    __syncthreads();

    // per-channel reduce: thread -> (row cl = tid>>2, seg = tid&3), 16 cols each
    {
        const int cl = tid >> 2, seg = tid & 3;
        float a = 0.f, b = 0.f;
        #pragma unroll
        for (int j = 0; j < 16; ++j) {
            a += sh1[cl][seg * 16 + j];
            b += sh2[cl][seg * 16 + j];
        }
        a += __shfl_down(a, 1, 64); b += __shfl_down(b, 1, 64);
        a += __shfl_down(a, 2, 64); b += __shfl_down(b, 2, 64);
        if (seg == 0)
            S12p[(size_t)(n * WIN + win) * 256 + q * 64 + cl] = make_float2(a, b);
    }

    // T^2 partial: combine 4 waves' position-local T, square, reduce
    if (tid < 64) {
        float4 a0 = shT[0][tid], a1 = shT[1][tid], a2 = shT[2][tid], a3 = shT[3][tid];
        const float tx = a0.x + a1.x + a2.x + a3.x;
        const float ty = a0.y + a1.y + a2.y + a3.y;
        const float tz = a0.z + a1.z + a2.z + a3.z;
        const float tw = a0.w + a1.w + a2.w + a3.w;
        float t2 = tx*tx + ty*ty + tz*tz + tw*tw;
        #pragma unroll
        for (int off = 32; off; off >>= 1) t2 += __shfl_down(t2, off, 64);
        if (tid == 0) pT2[bx] = t2;
    }
}

// ---- kernel 2: fold 13 window-partials -> S12[n*256+c] -------------------
__global__ __launch_bounds__(256) void fold_kernel(
    const float2* __restrict__ S12p, float2* __restrict__ S12)
{
    const int n = blockIdx.x, c = threadIdx.x;
    const float2* p = S12p + (size_t)n * WIN * 256 + c;
    float a = 0.f, b = 0.f;
    #pragma unroll
    for (int win = 0; win < WIN; ++win) {
        float2 v = p[(size_t)win * 256];
        a += v.x; b += v.y;
    }
    S12[n * 256 + c] = make_float2(a, b);
}

// ---- kernel 3: stats -> gates + compact norm coefficients ----------------
__global__ __launch_bounds__(256) void finalize_kernel(
    const float2* __restrict__ S12, const float* __restrict__ partialT2,
    const float* __restrict__ gate_logits, const float* __restrict__ diag_proj,
    float2* __restrict__ CB, float2* __restrict__ CL, float2* __restrict__ CG,
    float* __restrict__ GT)
{
    const int tid = threadIdx.x;
    __shared__ float sh_red1[4], sh_red2[4], sh_red3[4], sh_red4[4];

    const float inv_NHW  = 1.f / (float)NHW;
    const float inv_CHW  = 1.f / (float)(CC * 3136);
    const float inv_GHW  = 1.f / (float)GHW;
    const float inv_NCHW = 1.f / (float)NCHW;

    // BN: thread = channel
    const int c = tid;
    float s1 = 0.f, s2 = 0.f;
    for (int n = 0; n < NN; ++n) {
        float2 v = S12[n * CC + c];
        s1 += v.x; s2 += v.y;
    }
    const float mu_b  = s1 * inv_NHW;
    const float var_b = s2 * inv_NHW - mu_b * mu_b;
    CB[c] = make_float2(mu_b, rsqrtf(var_b + EPSF));

    // GN: thread = n*8+g
    const int ng_n = tid >> 3, ng_g = tid & 7;
    float s1g = 0.f, s2g = 0.f;
    for (int cc2 = 0; cc2 < CPG; ++cc2) {
        float2 v = S12[ng_n * CC + ng_g * CPG + cc2];
        s1g += v.x; s2g += v.y;
    }
    const float mu_g  = s1g * inv_GHW;
    const float var_g = s2g * inv_GHW - mu_g * mu_g;
    CG[tid] = make_float2(mu_g, rsqrtf(var_g + EPSF));

    // LN: reduce GN sums over the 8 groups of each sample
    float s1l = s1g, s2l = s2g;
    #pragma unroll
    for (int off = 1; off < 8; off <<= 1) {
        s1l += __shfl_xor(s1l, off, 64);
        s2l += __shfl_xor(s2l, off, 64);
    }
    float var_l_contrib = 0.f;
    if (ng_g == 0) {
        const float mu_l  = s1l * inv_CHW;
        const float var_l = s2l * inv_CHW - mu_l * mu_l;
        CL[ng_n] = make_float2(mu_l, rsqrtf(var_l + EPSF));
        var_l_contrib = var_l;
    }

    // T^2 partials
    float t2p = 0.f;
    for (int i = tid; i < NPT2; i += 256) t2p += partialT2[i];

    float r1 = var_b, r2 = s2, r3 = var_l_contrib, r4 = t2p;
    #pragma unroll
    for (int off = 32; off; off >>= 1) {
        r1 += __shfl_down(r1, off, 64);
        r2 += __shfl_down(r2, off, 64);
        r3 += __shfl_down(r3, off, 64);
        r4 += __shfl_down(r4, off, 64);
    }
    const int wave = tid >> 6, lane = tid & 63;
    if (lane == 0) { sh_red1[wave] = r1; sh_red2[wave] = r2; sh_red3[wave] = r3; sh_red4[wave] = r4; }
    __syncthreads();
    if (tid == 0) {
        const float sum_var_b = sh_red1[0] + sh_red1[1] + sh_red1[2] + sh_red1[3];
        const float total_x2  = sh_red2[0] + sh_red2[1] + sh_red2[2] + sh_red2[3];
        const float sum_var_l = sh_red3[0] + sh_red3[1] + sh_red3[2] + sh_red3[3];
        const float sum_T2    = sh_red4[0] + sh_red4[1] + sh_red4[2] + sh_red4[3];

        const float batch_var   = sum_var_b * (1.f / (float)CC);
        const float sample_var  = sum_var_l * (1.f / (float)NN);
        const float channel_var = total_x2 * inv_NCHW
                                - sum_T2 * inv_NHW * (1.f / ((float)CC * (float)CC));

        float desc[3];
        desc[0] = tanhf(logf(fmaxf(batch_var,   EPSF)));
        desc[1] = tanhf(logf(fmaxf(sample_var,  EPSF)));
        desc[2] = tanhf(logf(fmaxf(channel_var, EPSF)));

        float lg[3];
        #pragma unroll
        for (int i = 0; i < 3; ++i) {
            lg[i] = gate_logits[i] + diag_proj[i*3+0]*desc[0]
                                   + diag_proj[i*3+1]*desc[1]
                                   + diag_proj[i*3+2]*desc[2];
        }
        const float m = fmaxf(lg[0], fmaxf(lg[1], lg[2]));
        const float e0 = expf(lg[0]-m), e1 = expf(lg[1]-m), e2 = expf(lg[2]-m);
        const float inv = 1.f / (e0 + e1 + e2);
        GT[0] = e0 * inv; GT[1] = e1 * inv; GT[2] = e2 * inv;
    }
}

// ---- kernel 4: y = x*a + b; plain stores (retire into write-back L3) -----
__global__ __launch_bounds__(256) void apply_kernel(
    const f32x4* __restrict__ x4,
    const float* __restrict__ weight, const float* __restrict__ bias,
    const float2* __restrict__ CB, const float2* __restrict__ CL,
    const float2* __restrict__ CG, const float* __restrict__ GT,
    f32x4* __restrict__ y4)
{
    const int nc = blockIdx.x;
    const int n = nc >> 8, ch = nc & 255, g = ch >> 5;
    const float g0 = GT[0], g1 = GT[1], g2 = GT[2];
    const float2 cb = CB[ch], cl2 = CL[n], cg2 = CG[n * 8 + g];
    const float w = weight[ch], bi = bias[ch];
    const float scale = g0 * cb.y + g1 * cl2.y + g2 * cg2.y;
    const float offs  = g0 * cb.x * cb.y + g1 * cl2.x * cl2.y + g2 * cg2.x * cg2.y;
    const float a = w * scale;
    const float b = fmaf(-w, offs, bi);

    const f32x4* xp = x4 + (size_t)nc * HW4;
    f32x4* yp = y4 + (size_t)nc * HW4;
    const int tid = threadIdx.x;

    f32x4 v0 = xp[tid];
    f32x4 v1 = xp[tid + 256];
    f32x4 v2 = xp[tid + 512];
    f32x4 v3;
    if (tid < 16) v3 = xp[tid + 768];

    f32x4 r0, r1, r2, r3;
    r0.x = fmaf(v0.x, a, b); r0.y = fmaf(v0.y, a, b); r0.z = fmaf(v0.z, a, b); r0.w = fmaf(v0.w, a, b);
    r1.x = fmaf(v1.x, a, b); r1.y = fmaf(v1.y, a, b); r1.z = fmaf(v1.z, a, b); r1.w = fmaf(v1.w, a, b);
    r2.x = fmaf(v2.x, a, b); r2.y = fmaf(v2.y, a, b); r2.z = fmaf(v2.z, a, b); r2.w = fmaf(v2.w, a, b);
    yp[tid] = r0;
    yp[tid + 256] = r1;
    yp[tid + 512] = r2;
    if (tid < 16) {
        r3.x = fmaf(v3.x, a, b); r3.y = fmaf(v3.y, a, b); r3.z = fmaf(v3.z, a, b); r3.w = fmaf(v3.w, a, b);
        yp[tid + 768] = r3;
    }
}

extern "C" void kernel_launch(void* const* d_in, const int* in_sizes, int n_in,
                              void* d_out, int out_size, void* d_ws, size_t ws_size,
                              hipStream_t stream) {
    const float* x           = (const float*)d_in[0];
    const float* weight      = (const float*)d_in[1];
    const float* bias        = (const float*)d_in[2];
    const float* gate_logits = (const float*)d_in[3];
    const float* diag_proj   = (const float*)d_in[4];
    float* out = (float*)d_out;

    // ws layout (float offsets; all float2 users even-aligned)
    float* ws    = (float*)d_ws;
    float2* S12p = (float2*)ws;                  // NN*WIN*256 float2 = 212992 f
    float2* S12  = (float2*)(ws + 212992);       // 8192 float2 = 16384 f
    float2* CB   = (float2*)(ws + 229376);       // 256 float2
    float2* CL   = (float2*)(ws + 229888);       // 32 float2
    float2* CG   = (float2*)(ws + 229952);       // 256 float2
    float*  GT   = ws + 230464;                  // 4
    float*  pT2  = ws + 230468;                  // 1664

    stats_kernel<<<NSTAT, 256, 0, stream>>>((const float4*)x, S12p, pT2);
    fold_kernel<<<NN, 256, 0, stream>>>(S12p, S12);
    finalize_kernel<<<1, 256, 0, stream>>>(S12, pT2, gate_logits, diag_proj,
                                           CB, CL, CG, GT);
    apply_kernel<<<NN * CC, 256, 0, stream>>>((const f32x4*)x, weight, bias,
                                              CB, CL, CG, GT, (f32x4*)out);
}